// Round 7
// baseline (25.898 us; speedup 1.0000x reference)
//
#include <hip/hip_runtime.h>

#define N_ATOMS  1536
#define FEAT     32
#define N_GAUSS  16
#define MAXNBR   128
#define APB      4                    // atoms per block (1 per wave)
#define NBLK     (N_ATOMS / APB)      // 384
#define NTHREADS 256

// Fused: shared neighbor scan (4 atoms/block), per-wave aggregation + MLP,
// last-block-done global reduction (agent-scope atomics for cross-XCD safety).
__global__ __launch_bounds__(NTHREADS) void gnn_fused_kernel(
    const float* __restrict__ xyz, const int* __restrict__ z,
    const float* __restrict__ emb, const float* __restrict__ W1,
    const float* __restrict__ b1,  const float* __restrict__ W2,
    const float* __restrict__ b2,  const float* __restrict__ W3,
    const float* __restrict__ b3,
    float* __restrict__ e_atom, int* __restrict__ counter,
    float* __restrict__ out)
{
    const int tid  = threadIdx.x;
    const int lane = tid & 63;
    const int w    = tid >> 6;           // wave id 0..3
    const int a0   = blockIdx.x * APB;

    __shared__ float s_px[APB], s_py[APB], s_pz[APB];
    __shared__ int   s_nbr[APB][MAXNBR];
    __shared__ float s_dist[APB][MAXNBR];
    __shared__ float s_x[APB][FEAT];
    __shared__ int   s_cnt[APB];
    __shared__ int   s_last;
    __shared__ float s_red[4];

    if (tid < APB) {
        s_cnt[tid] = 0;
        s_px[tid] = xyz[3*(a0+tid)+0];
        s_py[tid] = xyz[3*(a0+tid)+1];
        s_pz[tid] = xyz[3*(a0+tid)+2];
    }
    __syncthreads();

    // ---- Phase A: ONE shared scan over all atoms (6 iters), 4 distance sets ----
    for (int j = tid; j < N_ATOMS; j += NTHREADS) {
        const float pjx = xyz[3*j+0], pjy = xyz[3*j+1], pjz = xyz[3*j+2];
        #pragma unroll
        for (int q = 0; q < APB; ++q) {
            float dx = pjx - s_px[q];
            float dy = pjy - s_py[q];
            float dz = pjz - s_pz[q];
            dx += (dx < -15.0f ? 30.0f : 0.0f) - (dx >= 15.0f ? 30.0f : 0.0f);
            dy += (dy < -15.0f ? 30.0f : 0.0f) - (dy >= 15.0f ? 30.0f : 0.0f);
            dz += (dz < -15.0f ? 30.0f : 0.0f) - (dz >= 15.0f ? 30.0f : 0.0f);
            float d2 = dx*dx + dy*dy + dz*dz;
            if (d2 < 25.0f && d2 > 0.0f) {
                int slot = atomicAdd(&s_cnt[q], 1);
                if (slot < MAXNBR) { s_nbr[q][slot] = j; s_dist[q][slot] = sqrtf(d2); }
            }
        }
    }
    __syncthreads();

    // ---- Phase B: wave w handles atom a0+w; 8 lanes/pair, 4 features/lane ----
    const int cnt  = min(s_cnt[w], MAXNBR);
    const int fl   = lane & 7;
    const int slot = lane >> 3;
    const float4 b1v = *(const float4*)&b1[fl*4];
    float af[4] = {0.0f, 0.0f, 0.0f, 0.0f};

    for (int p = slot; p < cnt; p += 8) {
        const int   j  = s_nbr[w][p];
        const float d  = s_dist[w][p];
        const int   zj = z[j];
        float s0 = b1v.x, s1 = b1v.y, s2 = b1v.z, s3 = b1v.w;
        #pragma unroll
        for (int g = 0; g < N_GAUSS; ++g) {
            float t = d - (float)g * (5.0f / 15.0f);
            float r = __expf(-10.0f * t * t);
            const float4 wv = *(const float4*)&W1[g * FEAT + fl * 4];
            s0 = fmaf(r, wv.x, s0); s1 = fmaf(r, wv.y, s1);
            s2 = fmaf(r, wv.z, s2); s3 = fmaf(r, wv.w, s3);
        }
        const float4 hj = *(const float4*)&emb[zj * FEAT + fl * 4];
        float sv[4] = {s0, s1, s2, s3};
        float hv[4] = {hj.x, hj.y, hj.z, hj.w};
        #pragma unroll
        for (int ff = 0; ff < 4; ++ff) {
            float t2 = __expf(-2.0f * fabsf(sv[ff]));
            float th = copysignf((1.0f - t2) / (1.0f + t2), sv[ff]);
            af[ff] = fmaf(th, hv[ff], af[ff]);
        }
    }
    #pragma unroll
    for (int ff = 0; ff < 4; ++ff) {
        af[ff] += __shfl_xor(af[ff], 8,  64);
        af[ff] += __shfl_xor(af[ff], 16, 64);
        af[ff] += __shfl_xor(af[ff], 32, 64);
    }
    if (lane < 8) {
        const float4 hi = *(const float4*)&emb[z[a0 + w] * FEAT + lane * 4];
        s_x[w][lane*4+0] = af[0] + hi.x;
        s_x[w][lane*4+1] = af[1] + hi.y;
        s_x[w][lane*4+2] = af[2] + hi.z;
        s_x[w][lane*4+3] = af[3] + hi.w;
    }
    __syncthreads();

    // ---- per-atom MLP on lanes 0..31 of wave w ----
    float e = 0.0f;
    if (lane < FEAT) {
        float s = b2[lane];
        #pragma unroll
        for (int k = 0; k < FEAT; ++k)
            s = fmaf(s_x[w][k], W2[k * FEAT + lane], s);
        float u = s / (1.0f + __expf(-s));     // silu
        e = u * W3[lane];
    }
    e += __shfl_xor(e, 16, 64);
    e += __shfl_xor(e, 8,  64);
    e += __shfl_xor(e, 4,  64);
    e += __shfl_xor(e, 2,  64);
    e += __shfl_xor(e, 1,  64);
    if (lane == 0)
        __hip_atomic_store(&e_atom[a0 + w], e, __ATOMIC_RELAXED, __HIP_MEMORY_SCOPE_AGENT);

    // ---- last-block-done reduction ----
    __syncthreads();   // all 4 waves' e_atom stores issued before the release RMW
    if (tid == 0) {
        int old = __hip_atomic_fetch_add(counter, 1, __ATOMIC_ACQ_REL, __HIP_MEMORY_SCOPE_AGENT);
        s_last = (old == NBLK - 1);
    }
    __syncthreads();
    if (s_last) {
        float s = 0.0f;
        #pragma unroll
        for (int k = 0; k < N_ATOMS / NTHREADS; ++k)
            s += __hip_atomic_load(&e_atom[tid + k * NTHREADS],
                                   __ATOMIC_RELAXED, __HIP_MEMORY_SCOPE_AGENT);
        #pragma unroll
        for (int off = 32; off > 0; off >>= 1)
            s += __shfl_xor(s, off, 64);
        if (lane == 0) s_red[w] = s;
        __syncthreads();
        if (tid == 0)
            out[0] = s_red[0] + s_red[1] + s_red[2] + s_red[3]
                   + (float)N_ATOMS * b3[0];
    }
}

extern "C" void kernel_launch(void* const* d_in, const int* in_sizes, int n_in,
                              void* d_out, int out_size, void* d_ws, size_t ws_size,
                              hipStream_t stream) {
    const float* xyz = (const float*)d_in[0];
    const int*   z   = (const int*)  d_in[1];
    const float* emb = (const float*)d_in[2];
    const float* W1  = (const float*)d_in[3];
    const float* b1  = (const float*)d_in[4];
    const float* W2  = (const float*)d_in[5];
    const float* b2  = (const float*)d_in[6];
    const float* W3  = (const float*)d_in[7];
    const float* b3  = (const float*)d_in[8];
    float* out     = (float*)d_out;
    int*   counter = (int*)d_ws;                         // 4 B
    float* e_atom  = (float*)((char*)d_ws + 256);        // own cacheline region

    hipMemsetAsync(counter, 0, sizeof(int), stream);     // reset each replay
    gnn_fused_kernel<<<NBLK, NTHREADS, 0, stream>>>(
        xyz, z, emb, W1, b1, W2, b2, W3, b3, e_atom, counter, out);
}